// Round 15
// baseline (98.345 us; speedup 1.0000x reference)
//
#include <hip/hip_runtime.h>
#include <hip/hip_bf16.h>
#include <stdint.h>

// ---------------- problem constants ----------------
#define BATCH 16
#define CDIM  1024
#define FWID  32
#define HW    1024
#define NA    1024
#define NTOT  (BATCH*NA)    // 16384
#define NCHUNK 16           // 4 mi-tiles * 4 wc waves = 16 chunks of 64 cols
#define MARGIN 0.6f
#define TPITCH 1088         // transposed-buffer row pitch in us (2176B, non-pow2: 2^6*17)

typedef __bf16 bf16x8 __attribute__((ext_vector_type(8)));
typedef float  f32x4  __attribute__((ext_vector_type(4)));
typedef unsigned short us4 __attribute__((ext_vector_type(4)));
typedef unsigned short us8 __attribute__((ext_vector_type(8)));
typedef float  f4     __attribute__((ext_vector_type(4)));

template<int OFF>
__device__ __forceinline__ us4 tr_read(uint32_t addr){
  us4 r;
  asm volatile("ds_read_b64_tr_b16 %0, %1 offset:%2" : "=v"(r) : "v"(addr), "n"(OFF));
  return r;
}

__device__ __forceinline__ void gload16(const unsigned short* g, unsigned short* l){
  __builtin_amdgcn_global_load_lds((const __attribute__((address_space(1))) void*)g,
                                   (__attribute__((address_space(3))) void*)l, 16, 0, 0);
}

union FragU  { us4 h[2]; bf16x8 v; };
union FragU8 { us8 u;    bf16x8 v; };

__device__ __forceinline__ void ins3(float& a, float& b, float& c, float v){
  if (v < c){
    c = v;
    if (c < b){ float t=b; b=c; c=t;
      if (b < a){ t=a; a=b; b=t; }
    }
  }
}

#define MFMA __builtin_amdgcn_mfma_f32_16x16x32_bf16

// ---------------------------------------------------------------------------
// Pass 1 (v5): fp32 [c][hw] -> bf16 [hw][c] (pitch TPITCH), DENSE reads.
// grid: e(2) x b(16) x cT(16) = 512 blocks, 512 threads.
// Phase A: wave w reads rows c = cT*64 + w*8 + rr, each instruction 1KB
// contiguous (64 lanes x f4); register cvt; scatter bf16 into LDS tileT
// [1024 hw][68 us pitch].  Phase B: per hw-row, 8 lanes read 16B each and
// store a dense 128B segment to the padded global row + accumulate norms.
// ---------------------------------------------------------------------------
__global__ __launch_bounds__(512)
void convert_transpose5(const float* __restrict__ S, const float* __restrict__ R,
                        unsigned short* __restrict__ tS, unsigned short* __restrict__ tR,
                        float* __restrict__ pnorm){
  __shared__ unsigned short tileT[1024*68];   // 139,264 B

  const int blk = blockIdx.x;
  const int e   = blk >> 8;
  const int b   = (blk >> 4) & 15;
  const int cT  = blk & 15;
  const float* src = (e ? R : S) + (size_t)b*CDIM*HW;
  unsigned short* dst = (e ? tR : tS) + (size_t)b*HW*TPITCH;

  const int t = threadIdx.x;
  const int w = t >> 6, l = t & 63;
  const int c0 = cT*64 + w*8;

  // ---- phase A: dense reads + in-LDS transpose ----
  #pragma unroll
  for (int rr = 0; rr < 8; ++rr){
    const float* srow = src + (size_t)(c0 + rr)*HW;
    #pragma unroll
    for (int i = 0; i < 4; ++i){
      const int hwb = i*256 + l*4;
      const f4 v = *(const f4*)&srow[hwb];
      #pragma unroll
      for (int s = 0; s < 4; ++s){
        __hip_bfloat16 h = __float2bfloat16(v[s]);
        tileT[(hwb + s)*68 + w*8 + rr] = __builtin_bit_cast(unsigned short, h);
      }
    }
  }
  __syncthreads();

  // ---- phase B: dense 128B global writes + norm partials ----
  const int r8 = t >> 3;        // 0..63
  const int sg = t & 7;         // c-octet within the 64-c slice
  #pragma unroll
  for (int k = 0; k < 16; ++k){
    const int h = r8 + 64*k;
    const unsigned short* row = &tileT[h*68 + sg*8];
    us8 pk;
    #pragma unroll
    for (int j = 0; j < 8; ++j) pk[j] = row[j];
    *(us8*)&dst[(size_t)h*TPITCH + cT*64 + sg*8] = pk;
    float sq = 0.f;
    #pragma unroll
    for (int j = 0; j < 8; ++j){
      const float g = __bfloat162float(__builtin_bit_cast(__hip_bfloat16, pk[j]));
      sq = fmaf(g, g, sq);
    }
    sq += __shfl_xor(sq, 1);
    sq += __shfl_xor(sq, 2);
    sq += __shfl_xor(sq, 4);
    if (sg == 0)
      pnorm[((size_t)(e*16 + b)*16 + cT)*HW + h] = sq;
  }
}

// grid: 32 blocks [e*16+b], 256 threads; snorm = sqrt(sum of 16 partials)
__global__ __launch_bounds__(256)
void norm_reduce16(const float* __restrict__ pnorm, float* __restrict__ snorm){
  const int eb = blockIdx.x;
  const int t  = threadIdx.x;
  #pragma unroll
  for (int r = 0; r < 4; ++r){
    const int hw = r*256 + t;
    float a = 0.f;
    #pragma unroll
    for (int ct = 0; ct < 16; ++ct)
      a += pnorm[((size_t)eb*16 + ct)*HW + hw];
    snorm[(size_t)eb*HW + hw] = sqrtf(a);
  }
}

// ---------------------------------------------------------------------------
// Pass 2 (v9p): round-13's proven GEMM, staging row stride = TPITCH (2176B,
// non-pow2) to break the 2KB stride aliasing in panel reads.  Otherwise
// byte-identical: 256x256 / 8-wave, BK=64, 2 bufs, 1 barrier/tile, 8-chunk
// XOR swizzle (each staged row a contiguous 128B global segment).
// ---------------------------------------------------------------------------
__global__ __launch_bounds__(512, 2)
void fused_gemm_top3_v9p(const unsigned short* __restrict__ tS,
                         const unsigned short* __restrict__ tR,
                         const float* __restrict__ snorm,
                         const int*   __restrict__ anchor,
                         const int*   __restrict__ posidx,
                         float* __restrict__ wtop,   // [NTOT][NCHUNK][3]
                         float* __restrict__ wpos)   // [NTOT]
{
  __shared__ unsigned short stage[65536];
  __shared__ int   p_lds[256], q_lds[256];
  __shared__ float nAs[256], nBs[256];      // RECIPROCAL norms

  const int t = threadIdx.x;
  const uint32_t bid = blockIdx.x;
  const uint32_t L = (bid & 7u)*32u + (bid >> 3);   // XCD swizzle (256%8==0)
  const int b  = L >> 4;
  const int ni = (L >> 2) & 3;
  const int mi = L & 3;

  const unsigned short* SbT = tS + (size_t)b*HW*TPITCH;
  const unsigned short* RbT = tR + (size_t)b*HW*TPITCH;

  if (t < 256){
    const int n_g = ni*256 + t;
    const int* ap = anchor + (size_t)(b*NA + n_g)*3;
    const int* pp = posidx + (size_t)(b*NA + n_g)*3;
    const int pv = ap[2]*FWID + ap[1];
    p_lds[t] = pv;
    q_lds[t] = pp[2]*FWID + pp[1];
    nAs[t] = 1.0f / snorm[(size_t)b*HW + pv];
  } else {
    nBs[t-256] = 1.0f / snorm[(size_t)(BATCH + b)*HW + mi*256 + (t-256)];
  }
  __syncthreads();

  const int l  = t & 63;
  const int w  = t >> 6;
  const int wr = w >> 2, wc = w & 3;

  const int gkc = (l&7) ^ ((l>>3)&7);
  const unsigned short* gA[4];
  const unsigned short* gB[4];
  #pragma unroll
  for (int i = 0; i < 4; ++i){
    const int row = w*32 + i*8 + (l>>3);
    gA[i] = SbT + (size_t)p_lds[row]*TPITCH + gkc*8;
    gB[i] = RbT + (size_t)(mi*256 + row)*TPITCH + gkc*8;
  }
  unsigned short* lA = &stage[w*2048];
  unsigned short* lB = &stage[32768 + w*2048];

  const int fb0 = (l&15)*64 + (((l>>4)    ) ^ (l&7))*8;
  const int fb1 = (l&15)*64 + (((l>>4) + 4) ^ (l&7))*8;
  const int abase = wr*8192;            // wr*128 rows * 64 us
  const int bbase = 32768 + wc*4096;    // wc*64 rows * 64 us

  f32x4 acc[8][4];
  #pragma unroll
  for (int i=0;i<8;i++){
    #pragma unroll
    for (int j=0;j<4;j++){ f32x4 z = {0.f,0.f,0.f,0.f}; acc[i][j] = z; }
  }

  auto stage8 = [&](int bo, int kt){
    const int ko = kt*64;   // 128 B per row per tile
    #pragma unroll
    for (int i = 0; i < 4; ++i){
      gload16(gA[i] + ko, lA + bo + i*512);
      gload16(gB[i] + ko, lB + bo + i*512);
    }
  };

  auto half = [&](int bo, int fbh){
    FragU8 Bf[4], Af[8];
    #pragma unroll
    for (int fb=0; fb<4; ++fb) Bf[fb].u = *(const us8*)&stage[bbase + bo + fb*1024 + fbh];
    #pragma unroll
    for (int fa=0; fa<8; ++fa) Af[fa].u = *(const us8*)&stage[abase + bo + fa*1024 + fbh];
    __builtin_amdgcn_s_setprio(1);
    #pragma unroll
    for (int fa=0; fa<8; ++fa){
      #pragma unroll
      for (int fb=0; fb<4; ++fb)
        acc[fa][fb] = MFMA(Af[fa].v, Bf[fb].v, acc[fa][fb], 0,0,0);
    }
    __builtin_amdgcn_s_setprio(0);
  };

  // ---- main K loop: 16 tiles of BK=64, 2 bufs, 1 barrier/tile ----
  stage8(0, 0);
  int bo = 0;
  for (int kt = 0; kt < 16; ++kt){
    asm volatile("s_waitcnt vmcnt(0)" ::: "memory");  // tile kt landed (aged 1 full tile)
    __builtin_amdgcn_s_barrier();
    __builtin_amdgcn_sched_barrier(0);
    if (kt < 15) stage8(bo ^ 16384, kt+1);
    half(bo, fb0);
    half(bo, fb1);
    bo ^= 16384;
  }

  // ---- epilogue: reciprocal norms + LDS two-phase top3 (proven) ----
  __syncthreads();
  float* tls = (float*)&stage[0] + (size_t)w*1152;

  float rinv[4];
  #pragma unroll
  for (int fb=0; fb<4; ++fb) rinv[fb] = nBs[wc*64 + fb*16 + (l&15)];

  #pragma unroll
  for (int fa=0; fa<8; ++fa){
    #pragma unroll
    for (int r=0; r<4; ++r){
      const int rg    = (l>>4)*4 + r;
      const int row_l = wr*128 + fa*16 + rg;
      const float ain = nAs[row_l];
      const float v0 = acc[fa][0][r] * ain * rinv[0];
      const float v1 = acc[fa][1][r] * ain * rinv[1];
      const float v2 = acc[fa][2][r] * ain * rinv[2];
      const float v3 = acc[fa][3][r] * ain * rinv[3];

      const int n_g = ni*256 + row_l;
      const int q   = q_lds[row_l];
      const int ql  = q - (mi*256 + wc*64);
      if (ql >= 0 && ql < 64 && (ql & 15) == (l & 15)){
        const int sel = ql >> 4;
        const float pv = sel==0 ? v0 : sel==1 ? v1 : sel==2 ? v2 : v3;
        wpos[b*NA + n_g] = pv;
      }

      float x=1e30f, y=1e30f, z=1e30f;
      ins3(x,y,z,v0); ins3(x,y,z,v1); ins3(x,y,z,v2); ins3(x,y,z,v3);
      f4 tr = {x, y, z, 0.f};
      *(f4*)(tls + (rg*17 + (l&15))*4) = tr;
    }
    asm volatile("s_waitcnt lgkmcnt(0)" ::: "memory");
    __builtin_amdgcn_sched_barrier(0);

    {
      const int rr = l >> 2;
      const float* rbp = tls + (rr*17 + (l&3)*4)*4;
      const f4 t0 = *(const f4*)(rbp);
      const f4 t1 = *(const f4*)(rbp + 4);
      const f4 t2 = *(const f4*)(rbp + 8);
      const f4 t3 = *(const f4*)(rbp + 12);
      float x = t0[0], y = t0[1], z = t0[2];
      ins3(x,y,z,t1[0]); ins3(x,y,z,t1[1]); ins3(x,y,z,t1[2]);
      ins3(x,y,z,t2[0]); ins3(x,y,z,t2[1]); ins3(x,y,z,t2[2]);
      ins3(x,y,z,t3[0]); ins3(x,y,z,t3[1]); ins3(x,y,z,t3[2]);
      #pragma unroll
      for (int m=1; m<4; m<<=1){
        const float ox = __shfl_xor(x, m);
        const float oy = __shfl_xor(y, m);
        const float oz = __shfl_xor(z, m);
        ins3(x,y,z,ox); ins3(x,y,z,oy); ins3(x,y,z,oz);
      }
      if ((l & 3) == 0){
        const int n_g = ni*256 + wr*128 + fa*16 + rr;
        float* dst = wtop + ((size_t)(b*NA + n_g)*NCHUNK + (mi*4 + wc))*3;
        dst[0]=x; dst[1]=y; dst[2]=z;
      }
    }
    asm volatile("s_waitcnt lgkmcnt(0)" ::: "memory");
    __builtin_amdgcn_sched_barrier(0);
  }
}

// ---------------------------------------------------------------------------
// v1 (verified) fused kernel — fallback when workspace is too small.
// ---------------------------------------------------------------------------
__global__ __launch_bounds__(256)
void fused_gemm_top3_v1(const float* __restrict__ sketch,
                        const float* __restrict__ refk,
                        const int*   __restrict__ anchor,
                        const int*   __restrict__ posidx,
                        float* __restrict__ wtop,
                        float* __restrict__ wpos)
{
  __shared__ union {
    unsigned short stage[16384];
    struct { float nA[16][128]; float nB[16][128]; } nrm;
  } sh;
  __shared__ int   p_lds[128];
  __shared__ float nA2[128], nB2[128];

  const int t = threadIdx.x;
  const uint32_t bid = blockIdx.x;
  const uint32_t L = (bid & 7u)*128u + (bid >> 3);
  const int b  = L >> 6;
  const int ni = (L >> 3) & 7;
  const int mi = L & 7;

  const float* Sb = sketch + (size_t)b*CDIM*HW;
  const float* Rb = refk   + (size_t)b*CDIM*HW;

  if (t < 128){
    const int n_g = ni*128 + t;
    const int* ap = anchor + (size_t)(b*NA + n_g)*3;
    p_lds[t] = ap[2]*FWID + ap[1];
  }
  __syncthreads();
  const int p0 = p_lds[0];
  int okf = 1;
  if (t < 128) okf = (p_lds[t] == p0 + t);
  const int contig = __syncthreads_and(okf);

  const int colg = (t & 15)*8;
  const int rowg = t >> 4;
  const int mbase = mi*128;

  const int l  = t & 63;
  const int w  = t >> 6;
  const int wr = w >> 1, wc = w & 1;
  const uint32_t sh_base = (uint32_t)(uintptr_t)&sh.stage[0];
  const uint32_t laneA = ((uint32_t)(l>>4))*2048u + (uint32_t)wr*512u + (uint32_t)(l&15)*8u;
  const uint32_t laneB = ((uint32_t)(l>>4))*2048u + (uint32_t)wc*512u + (uint32_t)(l&15)*8u;
  const int off0 = ((rowg>>2)*8 + (colg>>4))*64 + (rowg&3)*16 + (colg&15);

  f32x4 acc[4][4];
  #pragma unroll
  for (int i=0;i<4;i++){
    #pragma unroll
    for (int j=0;j<4;j++){ f32x4 z = {0.f,0.f,0.f,0.f}; acc[i][j] = z; }
  }

  float sqA[8] = {0,0,0,0,0,0,0,0};
  float sqB[8] = {0,0,0,0,0,0,0,0};
  f4 ra[4], rb[4];

  auto load_tile = [&](int kt){
    const int c0 = kt*32 + rowg;
    const float* SA = Sb + (size_t)c0*HW;
    const float* RB = Rb + (size_t)c0*HW + mbase + colg;
    if (contig){
      const float* pA = SA + p0 + colg;
      ra[0] = *(const f4*)(pA);
      ra[1] = *(const f4*)(pA + 4);
      ra[2] = *(const f4*)(pA + 16*HW);
      ra[3] = *(const f4*)(pA + 16*HW + 4);
    } else {
      float* raf = (float*)ra;
      #pragma unroll
      for (int i=0;i<8;i++){
        const int pc = p_lds[colg + i];
        raf[i]   = SA[pc];
        raf[8+i] = SA[16*HW + pc];
      }
    }
    rb[0] = *(const f4*)(RB);
    rb[1] = *(const f4*)(RB + 4);
    rb[2] = *(const f4*)(RB + 16*HW);
    rb[3] = *(const f4*)(RB + 16*HW + 4);
  };

  auto cvt_store = [&](int buf){
    const float* raf = (const float*)ra;
    const float* rbf = (const float*)rb;
    us8 pk;
    #pragma unroll
    for (int i=0;i<8;i++){
      __hip_bfloat16 h = __float2bfloat16(raf[i]);
      pk[i] = __builtin_bit_cast(unsigned short, h);
      const float g = __bfloat162float(h);
      sqA[i] = fmaf(g, g, sqA[i]);
    }
    *(us8*)&sh.stage[buf*4096 + off0] = pk;
    #pragma unroll
    for (int i=0;i<8;i++){
      __hip_bfloat16 h = __float2bfloat16(raf[8+i]);
      pk[i] = __builtin_bit_cast(unsigned short, h);
      const float g = __bfloat162float(h);
      sqA[i] = fmaf(g, g, sqA[i]);
    }
    *(us8*)&sh.stage[buf*4096 + off0 + 2048] = pk;
    #pragma unroll
    for (int i=0;i<8;i++){
      __hip_bfloat16 h = __float2bfloat16(rbf[i]);
      pk[i] = __builtin_bit_cast(unsigned short, h);
      const float g = __bfloat162float(h);
      sqB[i] = fmaf(g, g, sqB[i]);
    }
    *(us8*)&sh.stage[8192 + buf*4096 + off0] = pk;
    #pragma unroll
    for (int i=0;i<8;i++){
      __hip_bfloat16 h = __float2bfloat16(rbf[8+i]);
      pk[i] = __builtin_bit_cast(unsigned short, h);
      const float g = __bfloat162float(h);
      sqB[i] = fmaf(g, g, sqB[i]);
    }
    *(us8*)&sh.stage[8192 + buf*4096 + off0 + 2048] = pk;
  };

  auto compute = [&](int buf){
    const uint32_t aaddr = sh_base + (uint32_t)buf*8192u + laneA;
    const uint32_t baddr = sh_base + 16384u + (uint32_t)buf*8192u + laneB;
    FragU A0,A1,A2,A3,B0,B1,B2,B3;
    A0.h[0]=tr_read<0>(aaddr);    A0.h[1]=tr_read<1024>(aaddr);
    A1.h[0]=tr_read<128>(aaddr);  A1.h[1]=tr_read<1152>(aaddr);
    A2.h[0]=tr_read<256>(aaddr);  A2.h[1]=tr_read<1280>(aaddr);
    A3.h[0]=tr_read<384>(aaddr);  A3.h[1]=tr_read<1408>(aaddr);
    B0.h[0]=tr_read<0>(baddr);    B0.h[1]=tr_read<1024>(baddr);
    B1.h[0]=tr_read<128>(baddr);  B1.h[1]=tr_read<1152>(baddr);
    B2.h[0]=tr_read<256>(baddr);  B2.h[1]=tr_read<1280>(baddr);
    B3.h[0]=tr_read<384>(baddr);  B3.h[1]=tr_read<1408>(baddr);
    asm volatile("s_waitcnt lgkmcnt(0)" ::: "memory");
    __builtin_amdgcn_sched_barrier(0);
    acc[0][0]=MFMA(A0.v,B0.v,acc[0][0],0,0,0);
    acc[0][1]=MFMA(A0.v,B1.v,acc[0][1],0,0,0);
    acc[0][2]=MFMA(A0.v,B2.v,acc[0][2],0,0,0);
    acc[0][3]=MFMA(A0.v,B3.v,acc[0][3],0,0,0);
    acc[1][0]=MFMA(A1.v,B0.v,acc[1][0],0,0,0);
    acc[1][1]=MFMA(A1.v,B1.v,acc[1][1],0,0,0);
    acc[1][2]=MFMA(A1.v,B2.v,acc[1][2],0,0,0);
    acc[1][3]=MFMA(A1.v,B3.v,acc[1][3],0,0,0);
    acc[2][0]=MFMA(A2.v,B0.v,acc[2][0],0,0,0);
    acc[2][1]=MFMA(A2.v,B1.v,acc[2][1],0,0,0);
    acc[2][2]=MFMA(A2.v,B2.v,acc[2][2],0,0,0);
    acc[2][3]=MFMA(A2.v,B3.v,acc[2][3],0,0,0);
    acc[3][0]=MFMA(A3.v,B0.v,acc[3][0],0,0,0);
    acc[3][1]=MFMA(A3.v,B1.v,acc[3][1],0,0,0);
    acc[3][2]=MFMA(A3.v,B2.v,acc[3][2],0,0,0);
    acc[3][3]=MFMA(A3.v,B3.v,acc[3][3],0,0,0);
  };

  load_tile(0);
  cvt_store(0);
  __syncthreads();
  int buf = 0;
  for (int kt = 0; kt < 32; ++kt){
    if (kt < 31) load_tile(kt+1);
    compute(buf);
    if (kt < 31) cvt_store(buf^1);
    __syncthreads();
    buf ^= 1;
  }

  #pragma unroll
  for (int i=0;i<8;i++) sh.nrm.nA[rowg][colg+i] = sqA[i];
  #pragma unroll
  for (int i=0;i<8;i++) sh.nrm.nB[rowg][colg+i] = sqB[i];
  __syncthreads();
  if (t < 128){
    float s = 0.f;
    #pragma unroll
    for (int r=0;r<16;r++) s += sh.nrm.nA[r][t];
    nA2[t] = s;
  } else {
    const int c2 = t - 128;
    float s = 0.f;
    #pragma unroll
    for (int r=0;r<16;r++) s += sh.nrm.nB[r][c2];
    nB2[c2] = s;
  }
  __syncthreads();

  float rncol[4];
  #pragma unroll
  for (int nf=0;nf<4;nf++) rncol[nf] = sqrtf(nB2[wc*64 + nf*16 + (l&15)]);

  #pragma unroll
  for (int mf=0; mf<4; ++mf){
    #pragma unroll
    for (int r=0; r<4; ++r){
      const int row_l = wr*64 + mf*16 + (l>>4)*4 + r;
      const int n_g   = ni*128 + row_l;
      const float an  = sqrtf(nA2[row_l]);
      const float v0 = acc[mf][0][r] / fmaxf(an*rncol[0], 1e-8f);
      const float v1 = acc[mf][1][r] / fmaxf(an*rncol[1], 1e-8f);
      const float v2 = acc[mf][2][r] / fmaxf(an*rncol[2], 1e-8f);
      const float v3 = acc[mf][3][r] / fmaxf(an*rncol[3], 1e-8f);

      const int* pp = posidx + (size_t)(b*NA + n_g)*3;
      const int q  = pp[2]*FWID + pp[1];
      const int ql = q - (mbase + wc*64);
      if (ql >= 0 && ql < 64 && (ql & 15) == (l & 15)){
        const int sel = ql >> 4;
        const float pv = sel==0 ? v0 : sel==1 ? v1 : sel==2 ? v2 : v3;
        wpos[b*NA + n_g] = pv;
      }

      float x=1e30f, y=1e30f, z=1e30f;
      ins3(x,y,z,v0); ins3(x,y,z,v1); ins3(x,y,z,v2); ins3(x,y,z,v3);
      #pragma unroll
      for (int m=1; m<16; m<<=1){
        const float ox = __shfl_xor(x, m);
        const float oy = __shfl_xor(y, m);
        const float oz = __shfl_xor(z, m);
        ins3(x,y,z,ox); ins3(x,y,z,oy); ins3(x,y,z,oz);
      }
      if ((l & 15) == 0){
        float* dst = wtop + ((size_t)(b*NA + n_g)*NCHUNK + (mi*2 + wc))*3;
        dst[0]=x; dst[1]=y; dst[2]=z;
      }
    }
  }
}

// ---------------------------------------------------------------------------
__global__ __launch_bounds__(256)
void merge_top3(const float* __restrict__ wtop, const float* __restrict__ wpos,
                float* __restrict__ partial){
  __shared__ float red[256];
  const int id = blockIdx.x*256 + threadIdx.x;
  const float* src = wtop + (size_t)id*(NCHUNK*3);
  float x=1e30f, y=1e30f, z=1e30f;
  #pragma unroll
  for (int i=0;i<NCHUNK*3;i++) ins3(x,y,z, src[i]);
  const float loss = fmaxf((x+y+z) - wpos[id] + MARGIN, 0.0f);
  red[threadIdx.x] = loss;
  __syncthreads();
  for (int s=128; s>0; s>>=1){
    if (threadIdx.x < s) red[threadIdx.x] += red[threadIdx.x+s];
    __syncthreads();
  }
  if (threadIdx.x == 0) partial[blockIdx.x] = red[0];
}

__global__ void final_sum(const float* __restrict__ partial, float* __restrict__ out){
  float v = partial[threadIdx.x];
  #pragma unroll
  for (int off=32; off>0; off>>=1) v += __shfl_down(v, off);
  if (threadIdx.x == 0) out[0] = v / (1e-6f + (float)NTOT);
}

// ---------------------------------------------------------------------------
extern "C" void kernel_launch(void* const* d_in, const int* in_sizes, int n_in,
                              void* d_out, int out_size, void* d_ws, size_t ws_size,
                              hipStream_t stream){
  const float* sketch = (const float*)d_in[0];
  const float* refk   = (const float*)d_in[1];
  const int*   anchor = (const int*)d_in[2];
  const int*   posidx = (const int*)d_in[3];
  float* out = (float*)d_out;

  float* wtop    = (float*)d_ws;                       // NTOT*NCHUNK*3 floats
  float* wpos    = wtop + (size_t)NTOT*NCHUNK*3;       // NTOT floats
  float* partial = wpos + NTOT;                        // 64 floats (+pad)
  unsigned short* tS = (unsigned short*)(partial + 256);
  unsigned short* tR = tS + (size_t)BATCH*HW*TPITCH;
  float* pnorm = (float*)(tR + (size_t)BATCH*HW*TPITCH);  // 32*16*1024 floats
  float* snorm = pnorm + (size_t)32*16*1024;              // 32*1024 floats
  const size_t need = (size_t)((char*)(snorm + 32*1024) - (char*)d_ws);

  if (ws_size >= need){
    convert_transpose5<<<dim3(512), dim3(512), 0, stream>>>(sketch, refk, tS, tR, pnorm);
    norm_reduce16<<<dim3(32), dim3(256), 0, stream>>>(pnorm, snorm);
    fused_gemm_top3_v9p<<<dim3(256), dim3(512), 0, stream>>>(tS, tR, snorm, anchor, posidx, wtop, wpos);
  } else {
    fused_gemm_top3_v1<<<dim3(1024), dim3(256), 0, stream>>>(sketch, refk, anchor, posidx, wtop, wpos);
  }
  merge_top3<<<dim3(64), dim3(256), 0, stream>>>(wtop, wpos, partial);
  final_sum<<<dim3(1), dim3(64), 0, stream>>>(partial, out);
}

// Round 16
// 95.215 us; speedup vs baseline: 1.0329x; 1.0329x over previous
//
#include <hip/hip_runtime.h>
#include <hip/hip_bf16.h>
#include <stdint.h>

// ---------------- problem constants ----------------
#define BATCH 16
#define CDIM  1024
#define FWID  32
#define HW    1024
#define NA    1024
#define NTOT  (BATCH*NA)    // 16384
#define NCHUNK 16           // 4 mi-tiles * 4 wc waves = 16 chunks of 64 cols
#define MARGIN 0.6f

typedef __bf16 bf16x8 __attribute__((ext_vector_type(8)));
typedef float  f32x4  __attribute__((ext_vector_type(4)));
typedef unsigned short us4 __attribute__((ext_vector_type(4)));
typedef unsigned short us8 __attribute__((ext_vector_type(8)));
typedef float  f4     __attribute__((ext_vector_type(4)));

template<int OFF>
__device__ __forceinline__ us4 tr_read(uint32_t addr){
  us4 r;
  asm volatile("ds_read_b64_tr_b16 %0, %1 offset:%2" : "=v"(r) : "v"(addr), "n"(OFF));
  return r;
}

__device__ __forceinline__ void gload16(const unsigned short* g, unsigned short* l){
  __builtin_amdgcn_global_load_lds((const __attribute__((address_space(1))) void*)g,
                                   (__attribute__((address_space(3))) void*)l, 16, 0, 0);
}

union FragU  { us4 h[2]; bf16x8 v; };
union FragU8 { us8 u;    bf16x8 v; };

__device__ __forceinline__ void ins3(float& a, float& b, float& c, float v){
  if (v < c){
    c = v;
    if (c < b){ float t=b; b=c; c=t;
      if (b < a){ t=a; a=b; b=t; }
    }
  }
}

#define MFMA __builtin_amdgcn_mfma_f32_16x16x32_bf16

// ---------------------------------------------------------------------------
// Pass 1 (v4, round-14 best): fp32 [c][hw] -> bf16 [hw][c].  Full 64x1024
// transposed tile staged in LDS; global writes fully dense (128 KB contiguous
// per block).  Per-hw norm completed in-block -> snorm written directly.
// grid: e(2) x b(16) x hwT(16) = 512 blocks, 512 threads.
// ---------------------------------------------------------------------------
__global__ __launch_bounds__(512)
void convert_transpose4(const float* __restrict__ S, const float* __restrict__ R,
                        unsigned short* __restrict__ tS, unsigned short* __restrict__ tR,
                        float* __restrict__ snorm){
  __shared__ unsigned short tile[64*1032];   // 132,096 B (pad 8 us/row)
  __shared__ float nsq[64][33];              // 8,448 B

  const int blk = blockIdx.x;
  const int e   = blk >> 8;
  const int b   = (blk >> 4) & 15;
  const int hwT = blk & 15;
  const float* src = (e ? R : S) + (size_t)b*CDIM*HW;
  unsigned short* dst = (e ? tR : tS) + (size_t)b*HW*CDIM;

  const int t  = threadIdx.x;
  const int li = t & 15;          // hw quad: hw = hwT*64 + li*4 + j
  const int gi = t >> 4;          // c-octet group 0..31
  const int hwb = hwT*64 + li*4;

  float sq0=0.f, sq1=0.f, sq2=0.f, sq3=0.f;
  #pragma unroll
  for (int it = 0; it < 4; ++it){
    const int cb = it*256 + gi*8;
    f4 col[8];
    #pragma unroll
    for (int i = 0; i < 8; ++i)
      col[i] = *(const f4*)&src[(size_t)(cb + i)*HW + hwb];
    #pragma unroll
    for (int j = 0; j < 4; ++j){
      us8 pk;
      float sq = 0.f;
      #pragma unroll
      for (int i = 0; i < 8; ++i){
        __hip_bfloat16 h = __float2bfloat16(col[i][j]);
        pk[i] = __builtin_bit_cast(unsigned short, h);
        const float g = __bfloat162float(h);
        sq = fmaf(g, g, sq);
      }
      *(us8*)&tile[(li*4 + j)*1032 + cb] = pk;
      if (j==0) sq0+=sq; else if (j==1) sq1+=sq; else if (j==2) sq2+=sq; else sq3+=sq;
    }
  }
  nsq[li*4+0][gi] = sq0;
  nsq[li*4+1][gi] = sq1;
  nsq[li*4+2][gi] = sq2;
  nsq[li*4+3][gi] = sq3;
  __syncthreads();

  // write phase: wave w -> rows w*8..w*8+7; per row 2 x 1KB dense stores.
  const int w = t >> 6, l = t & 63;
  #pragma unroll
  for (int rr = 0; rr < 8; ++rr){
    const int row = w*8 + rr;
    const us8 v0 = *(const us8*)&tile[row*1032 + l*8];
    const us8 v1 = *(const us8*)&tile[row*1032 + 512 + l*8];
    unsigned short* drow = dst + (size_t)(hwT*64 + row)*CDIM;
    *(us8*)(drow + l*8)       = v0;
    *(us8*)(drow + 512 + l*8) = v1;
  }

  if (t < 64){
    float a = 0.f;
    #pragma unroll
    for (int g2 = 0; g2 < 32; ++g2) a += nsq[t][g2];
    snorm[(size_t)(e*16 + b)*HW + hwT*64 + t] = sqrtf(a);
  }
}

// ---------------------------------------------------------------------------
// Pass 2 (v9, round-13/14 best): 256x256 / 8-wave, BK=64, 2 bufs (128 KB),
// ONE barrier per 64-K tile.  8-chunk XOR swizzle; each staged row is a
// contiguous 128B global segment.  0 bank conflicts measured.
// ---------------------------------------------------------------------------
__global__ __launch_bounds__(512, 2)
void fused_gemm_top3_v9(const unsigned short* __restrict__ tS,
                        const unsigned short* __restrict__ tR,
                        const float* __restrict__ snorm,
                        const int*   __restrict__ anchor,
                        const int*   __restrict__ posidx,
                        float* __restrict__ wtop,   // [NTOT][NCHUNK][3]
                        float* __restrict__ wpos)   // [NTOT]
{
  __shared__ unsigned short stage[65536];
  __shared__ int   p_lds[256], q_lds[256];
  __shared__ float nAs[256], nBs[256];      // RECIPROCAL norms

  const int t = threadIdx.x;
  const uint32_t bid = blockIdx.x;
  const uint32_t L = (bid & 7u)*32u + (bid >> 3);   // XCD swizzle (256%8==0)
  const int b  = L >> 4;
  const int ni = (L >> 2) & 3;
  const int mi = L & 3;

  const unsigned short* SbT = tS + (size_t)b*HW*CDIM;
  const unsigned short* RbT = tR + (size_t)b*HW*CDIM;

  if (t < 256){
    const int n_g = ni*256 + t;
    const int* ap = anchor + (size_t)(b*NA + n_g)*3;
    const int* pp = posidx + (size_t)(b*NA + n_g)*3;
    const int pv = ap[2]*FWID + ap[1];
    p_lds[t] = pv;
    q_lds[t] = pp[2]*FWID + pp[1];
    nAs[t] = 1.0f / snorm[(size_t)b*HW + pv];
  } else {
    nBs[t-256] = 1.0f / snorm[(size_t)(BATCH + b)*HW + mi*256 + (t-256)];
  }
  __syncthreads();

  const int l  = t & 63;
  const int w  = t >> 6;
  const int wr = w >> 2, wc = w & 3;

  const int gkc = (l&7) ^ ((l>>3)&7);
  const unsigned short* gA[4];
  const unsigned short* gB[4];
  #pragma unroll
  for (int i = 0; i < 4; ++i){
    const int row = w*32 + i*8 + (l>>3);
    gA[i] = SbT + (size_t)p_lds[row]*CDIM + gkc*8;
    gB[i] = RbT + (size_t)(mi*256 + row)*CDIM + gkc*8;
  }
  unsigned short* lA = &stage[w*2048];
  unsigned short* lB = &stage[32768 + w*2048];

  const int fb0 = (l&15)*64 + (((l>>4)    ) ^ (l&7))*8;
  const int fb1 = (l&15)*64 + (((l>>4) + 4) ^ (l&7))*8;
  const int abase = wr*8192;            // wr*128 rows * 64 us
  const int bbase = 32768 + wc*4096;    // wc*64 rows * 64 us

  f32x4 acc[8][4];
  #pragma unroll
  for (int i=0;i<8;i++){
    #pragma unroll
    for (int j=0;j<4;j++){ f32x4 z = {0.f,0.f,0.f,0.f}; acc[i][j] = z; }
  }

  auto stage8 = [&](int bo, int kt){
    const int ko = kt*64;   // 128 B per row per tile
    #pragma unroll
    for (int i = 0; i < 4; ++i){
      gload16(gA[i] + ko, lA + bo + i*512);
      gload16(gB[i] + ko, lB + bo + i*512);
    }
  };

  auto half = [&](int bo, int fbh){
    FragU8 Bf[4], Af[8];
    #pragma unroll
    for (int fb=0; fb<4; ++fb) Bf[fb].u = *(const us8*)&stage[bbase + bo + fb*1024 + fbh];
    #pragma unroll
    for (int fa=0; fa<8; ++fa) Af[fa].u = *(const us8*)&stage[abase + bo + fa*1024 + fbh];
    __builtin_amdgcn_s_setprio(1);
    #pragma unroll
    for (int fa=0; fa<8; ++fa){
      #pragma unroll
      for (int fb=0; fb<4; ++fb)
        acc[fa][fb] = MFMA(Af[fa].v, Bf[fb].v, acc[fa][fb], 0,0,0);
    }
    __builtin_amdgcn_s_setprio(0);
  };

  // ---- main K loop: 16 tiles of BK=64, 2 bufs, 1 barrier/tile ----
  stage8(0, 0);
  int bo = 0;
  for (int kt = 0; kt < 16; ++kt){
    asm volatile("s_waitcnt vmcnt(0)" ::: "memory");  // tile kt landed (aged 1 full tile)
    __builtin_amdgcn_s_barrier();
    __builtin_amdgcn_sched_barrier(0);
    if (kt < 15) stage8(bo ^ 16384, kt+1);
    half(bo, fb0);
    half(bo, fb1);
    bo ^= 16384;
  }

  // ---- epilogue: reciprocal norms + LDS two-phase top3 (proven) ----
  __syncthreads();
  float* tls = (float*)&stage[0] + (size_t)w*1152;

  float rinv[4];
  #pragma unroll
  for (int fb=0; fb<4; ++fb) rinv[fb] = nBs[wc*64 + fb*16 + (l&15)];

  #pragma unroll
  for (int fa=0; fa<8; ++fa){
    #pragma unroll
    for (int r=0; r<4; ++r){
      const int rg    = (l>>4)*4 + r;
      const int row_l = wr*128 + fa*16 + rg;
      const float ain = nAs[row_l];
      const float v0 = acc[fa][0][r] * ain * rinv[0];
      const float v1 = acc[fa][1][r] * ain * rinv[1];
      const float v2 = acc[fa][2][r] * ain * rinv[2];
      const float v3 = acc[fa][3][r] * ain * rinv[3];

      const int n_g = ni*256 + row_l;
      const int q   = q_lds[row_l];
      const int ql  = q - (mi*256 + wc*64);
      if (ql >= 0 && ql < 64 && (ql & 15) == (l & 15)){
        const int sel = ql >> 4;
        const float pv = sel==0 ? v0 : sel==1 ? v1 : sel==2 ? v2 : v3;
        wpos[b*NA + n_g] = pv;
      }

      float x=1e30f, y=1e30f, z=1e30f;
      ins3(x,y,z,v0); ins3(x,y,z,v1); ins3(x,y,z,v2); ins3(x,y,z,v3);
      f4 tr = {x, y, z, 0.f};
      *(f4*)(tls + (rg*17 + (l&15))*4) = tr;
    }
    asm volatile("s_waitcnt lgkmcnt(0)" ::: "memory");
    __builtin_amdgcn_sched_barrier(0);

    {
      const int rr = l >> 2;
      const float* rbp = tls + (rr*17 + (l&3)*4)*4;
      const f4 t0 = *(const f4*)(rbp);
      const f4 t1 = *(const f4*)(rbp + 4);
      const f4 t2 = *(const f4*)(rbp + 8);
      const f4 t3 = *(const f4*)(rbp + 12);
      float x = t0[0], y = t0[1], z = t0[2];
      ins3(x,y,z,t1[0]); ins3(x,y,z,t1[1]); ins3(x,y,z,t1[2]);
      ins3(x,y,z,t2[0]); ins3(x,y,z,t2[1]); ins3(x,y,z,t2[2]);
      ins3(x,y,z,t3[0]); ins3(x,y,z,t3[1]); ins3(x,y,z,t3[2]);
      #pragma unroll
      for (int m=1; m<4; m<<=1){
        const float ox = __shfl_xor(x, m);
        const float oy = __shfl_xor(y, m);
        const float oz = __shfl_xor(z, m);
        ins3(x,y,z,ox); ins3(x,y,z,oy); ins3(x,y,z,oz);
      }
      if ((l & 3) == 0){
        const int n_g = ni*256 + wr*128 + fa*16 + rr;
        float* dst = wtop + ((size_t)(b*NA + n_g)*NCHUNK + (mi*4 + wc))*3;
        dst[0]=x; dst[1]=y; dst[2]=z;
      }
    }
    asm volatile("s_waitcnt lgkmcnt(0)" ::: "memory");
    __builtin_amdgcn_sched_barrier(0);
  }
}

// ---------------------------------------------------------------------------
// v1 (verified) fused kernel — fallback when workspace is too small.
// ---------------------------------------------------------------------------
__global__ __launch_bounds__(256)
void fused_gemm_top3_v1(const float* __restrict__ sketch,
                        const float* __restrict__ refk,
                        const int*   __restrict__ anchor,
                        const int*   __restrict__ posidx,
                        float* __restrict__ wtop,
                        float* __restrict__ wpos)
{
  __shared__ union {
    unsigned short stage[16384];
    struct { float nA[16][128]; float nB[16][128]; } nrm;
  } sh;
  __shared__ int   p_lds[128];
  __shared__ float nA2[128], nB2[128];

  const int t = threadIdx.x;
  const uint32_t bid = blockIdx.x;
  const uint32_t L = (bid & 7u)*128u + (bid >> 3);
  const int b  = L >> 6;
  const int ni = (L >> 3) & 7;
  const int mi = L & 7;

  const float* Sb = sketch + (size_t)b*CDIM*HW;
  const float* Rb = refk   + (size_t)b*CDIM*HW;

  if (t < 128){
    const int n_g = ni*128 + t;
    const int* ap = anchor + (size_t)(b*NA + n_g)*3;
    p_lds[t] = ap[2]*FWID + ap[1];
  }
  __syncthreads();
  const int p0 = p_lds[0];
  int okf = 1;
  if (t < 128) okf = (p_lds[t] == p0 + t);
  const int contig = __syncthreads_and(okf);

  const int colg = (t & 15)*8;
  const int rowg = t >> 4;
  const int mbase = mi*128;

  const int l  = t & 63;
  const int w  = t >> 6;
  const int wr = w >> 1, wc = w & 1;
  const uint32_t sh_base = (uint32_t)(uintptr_t)&sh.stage[0];
  const uint32_t laneA = ((uint32_t)(l>>4))*2048u + (uint32_t)wr*512u + (uint32_t)(l&15)*8u;
  const uint32_t laneB = ((uint32_t)(l>>4))*2048u + (uint32_t)wc*512u + (uint32_t)(l&15)*8u;
  const int off0 = ((rowg>>2)*8 + (colg>>4))*64 + (rowg&3)*16 + (colg&15);

  f32x4 acc[4][4];
  #pragma unroll
  for (int i=0;i<4;i++){
    #pragma unroll
    for (int j=0;j<4;j++){ f32x4 z = {0.f,0.f,0.f,0.f}; acc[i][j] = z; }
  }

  float sqA[8] = {0,0,0,0,0,0,0,0};
  float sqB[8] = {0,0,0,0,0,0,0,0};
  f4 ra[4], rb[4];

  auto load_tile = [&](int kt){
    const int c0 = kt*32 + rowg;
    const float* SA = Sb + (size_t)c0*HW;
    const float* RB = Rb + (size_t)c0*HW + mbase + colg;
    if (contig){
      const float* pA = SA + p0 + colg;
      ra[0] = *(const f4*)(pA);
      ra[1] = *(const f4*)(pA + 4);
      ra[2] = *(const f4*)(pA + 16*HW);
      ra[3] = *(const f4*)(pA + 16*HW + 4);
    } else {
      float* raf = (float*)ra;
      #pragma unroll
      for (int i=0;i<8;i++){
        const int pc = p_lds[colg + i];
        raf[i]   = SA[pc];
        raf[8+i] = SA[16*HW + pc];
      }
    }
    rb[0] = *(const f4*)(RB);
    rb[1] = *(const f4*)(RB + 4);
    rb[2] = *(const f4*)(RB + 16*HW);
    rb[3] = *(const f4*)(RB + 16*HW + 4);
  };

  auto cvt_store = [&](int buf){
    const float* raf = (const float*)ra;
    const float* rbf = (const float*)rb;
    us8 pk;
    #pragma unroll
    for (int i=0;i<8;i++){
      __hip_bfloat16 h = __float2bfloat16(raf[i]);
      pk[i] = __builtin_bit_cast(unsigned short, h);
      const float g = __bfloat162float(h);
      sqA[i] = fmaf(g, g, sqA[i]);
    }
    *(us8*)&sh.stage[buf*4096 + off0] = pk;
    #pragma unroll
    for (int i=0;i<8;i++){
      __hip_bfloat16 h = __float2bfloat16(raf[8+i]);
      pk[i] = __builtin_bit_cast(unsigned short, h);
      const float g = __bfloat162float(h);
      sqA[i] = fmaf(g, g, sqA[i]);
    }
    *(us8*)&sh.stage[buf*4096 + off0 + 2048] = pk;
    #pragma unroll
    for (int i=0;i<8;i++){
      __hip_bfloat16 h = __float2bfloat16(rbf[i]);
      pk[i] = __builtin_bit_cast(unsigned short, h);
      const float g = __bfloat162float(h);
      sqB[i] = fmaf(g, g, sqB[i]);
    }
    *(us8*)&sh.stage[8192 + buf*4096 + off0] = pk;
    #pragma unroll
    for (int i=0;i<8;i++){
      __hip_bfloat16 h = __float2bfloat16(rbf[8+i]);
      pk[i] = __builtin_bit_cast(unsigned short, h);
      const float g = __bfloat162float(h);
      sqB[i] = fmaf(g, g, sqB[i]);
    }
    *(us8*)&sh.stage[8192 + buf*4096 + off0 + 2048] = pk;
  };

  auto compute = [&](int buf){
    const uint32_t aaddr = sh_base + (uint32_t)buf*8192u + laneA;
    const uint32_t baddr = sh_base + 16384u + (uint32_t)buf*8192u + laneB;
    FragU A0,A1,A2,A3,B0,B1,B2,B3;
    A0.h[0]=tr_read<0>(aaddr);    A0.h[1]=tr_read<1024>(aaddr);
    A1.h[0]=tr_read<128>(aaddr);  A1.h[1]=tr_read<1152>(aaddr);
    A2.h[0]=tr_read<256>(aaddr);  A2.h[1]=tr_read<1280>(aaddr);
    A3.h[0]=tr_read<384>(aaddr);  A3.h[1]=tr_read<1408>(aaddr);
    B0.h[0]=tr_read<0>(baddr);    B0.h[1]=tr_read<1024>(baddr);
    B1.h[0]=tr_read<128>(baddr);  B1.h[1]=tr_read<1152>(baddr);
    B2.h[0]=tr_read<256>(baddr);  B2.h[1]=tr_read<1280>(baddr);
    B3.h[0]=tr_read<384>(baddr);  B3.h[1]=tr_read<1408>(baddr);
    asm volatile("s_waitcnt lgkmcnt(0)" ::: "memory");
    __builtin_amdgcn_sched_barrier(0);
    acc[0][0]=MFMA(A0.v,B0.v,acc[0][0],0,0,0);
    acc[0][1]=MFMA(A0.v,B1.v,acc[0][1],0,0,0);
    acc[0][2]=MFMA(A0.v,B2.v,acc[0][2],0,0,0);
    acc[0][3]=MFMA(A0.v,B3.v,acc[0][3],0,0,0);
    acc[1][0]=MFMA(A1.v,B0.v,acc[1][0],0,0,0);
    acc[1][1]=MFMA(A1.v,B1.v,acc[1][1],0,0,0);
    acc[1][2]=MFMA(A1.v,B2.v,acc[1][2],0,0,0);
    acc[1][3]=MFMA(A1.v,B3.v,acc[1][3],0,0,0);
    acc[2][0]=MFMA(A2.v,B0.v,acc[2][0],0,0,0);
    acc[2][1]=MFMA(A2.v,B1.v,acc[2][1],0,0,0);
    acc[2][2]=MFMA(A2.v,B2.v,acc[2][2],0,0,0);
    acc[2][3]=MFMA(A2.v,B3.v,acc[2][3],0,0,0);
    acc[3][0]=MFMA(A3.v,B0.v,acc[3][0],0,0,0);
    acc[3][1]=MFMA(A3.v,B1.v,acc[3][1],0,0,0);
    acc[3][2]=MFMA(A3.v,B2.v,acc[3][2],0,0,0);
    acc[3][3]=MFMA(A3.v,B3.v,acc[3][3],0,0,0);
  };

  load_tile(0);
  cvt_store(0);
  __syncthreads();
  int buf = 0;
  for (int kt = 0; kt < 32; ++kt){
    if (kt < 31) load_tile(kt+1);
    compute(buf);
    if (kt < 31) cvt_store(buf^1);
    __syncthreads();
    buf ^= 1;
  }

  #pragma unroll
  for (int i=0;i<8;i++) sh.nrm.nA[rowg][colg+i] = sqA[i];
  #pragma unroll
  for (int i=0;i<8;i++) sh.nrm.nB[rowg][colg+i] = sqB[i];
  __syncthreads();
  if (t < 128){
    float s = 0.f;
    #pragma unroll
    for (int r=0;r<16;r++) s += sh.nrm.nA[r][t];
    nA2[t] = s;
  } else {
    const int c2 = t - 128;
    float s = 0.f;
    #pragma unroll
    for (int r=0;r<16;r++) s += sh.nrm.nB[r][c2];
    nB2[c2] = s;
  }
  __syncthreads();

  float rncol[4];
  #pragma unroll
  for (int nf=0;nf<4;nf++) rncol[nf] = sqrtf(nB2[wc*64 + nf*16 + (l&15)]);

  #pragma unroll
  for (int mf=0; mf<4; ++mf){
    #pragma unroll
    for (int r=0; r<4; ++r){
      const int row_l = wr*64 + mf*16 + (l>>4)*4 + r;
      const int n_g   = ni*128 + row_l;
      const float an  = sqrtf(nA2[row_l]);
      const float v0 = acc[mf][0][r] / fmaxf(an*rncol[0], 1e-8f);
      const float v1 = acc[mf][1][r] / fmaxf(an*rncol[1], 1e-8f);
      const float v2 = acc[mf][2][r] / fmaxf(an*rncol[2], 1e-8f);
      const float v3 = acc[mf][3][r] / fmaxf(an*rncol[3], 1e-8f);

      const int* pp = posidx + (size_t)(b*NA + n_g)*3;
      const int q  = pp[2]*FWID + pp[1];
      const int ql = q - (mbase + wc*64);
      if (ql >= 0 && ql < 64 && (ql & 15) == (l & 15)){
        const int sel = ql >> 4;
        const float pv = sel==0 ? v0 : sel==1 ? v1 : sel==2 ? v2 : v3;
        wpos[b*NA + n_g] = pv;
      }

      float x=1e30f, y=1e30f, z=1e30f;
      ins3(x,y,z,v0); ins3(x,y,z,v1); ins3(x,y,z,v2); ins3(x,y,z,v3);
      #pragma unroll
      for (int m=1; m<16; m<<=1){
        const float ox = __shfl_xor(x, m);
        const float oy = __shfl_xor(y, m);
        const float oz = __shfl_xor(z, m);
        ins3(x,y,z,ox); ins3(x,y,z,oy); ins3(x,y,z,oz);
      }
      if ((l & 15) == 0){
        float* dst = wtop + ((size_t)(b*NA + n_g)*NCHUNK + (mi*2 + wc))*3;
        dst[0]=x; dst[1]=y; dst[2]=z;
      }
    }
  }
}

// ---------------------------------------------------------------------------
__global__ __launch_bounds__(256)
void merge_top3(const float* __restrict__ wtop, const float* __restrict__ wpos,
                float* __restrict__ partial){
  __shared__ float red[256];
  const int id = blockIdx.x*256 + threadIdx.x;
  const float* src = wtop + (size_t)id*(NCHUNK*3);
  float x=1e30f, y=1e30f, z=1e30f;
  #pragma unroll
  for (int i=0;i<NCHUNK*3;i++) ins3(x,y,z, src[i]);
  const float loss = fmaxf((x+y+z) - wpos[id] + MARGIN, 0.0f);
  red[threadIdx.x] = loss;
  __syncthreads();
  for (int s=128; s>0; s>>=1){
    if (threadIdx.x < s) red[threadIdx.x] += red[threadIdx.x+s];
    __syncthreads();
  }
  if (threadIdx.x == 0) partial[blockIdx.x] = red[0];
}

__global__ void final_sum(const float* __restrict__ partial, float* __restrict__ out){
  float v = partial[threadIdx.x];
  #pragma unroll
  for (int off=32; off>0; off>>=1) v += __shfl_down(v, off);
  if (threadIdx.x == 0) out[0] = v / (1e-6f + (float)NTOT);
}

// ---------------------------------------------------------------------------
extern "C" void kernel_launch(void* const* d_in, const int* in_sizes, int n_in,
                              void* d_out, int out_size, void* d_ws, size_t ws_size,
                              hipStream_t stream){
  const float* sketch = (const float*)d_in[0];
  const float* refk   = (const float*)d_in[1];
  const int*   anchor = (const int*)d_in[2];
  const int*   posidx = (const int*)d_in[3];
  float* out = (float*)d_out;

  float* wtop    = (float*)d_ws;                       // NTOT*NCHUNK*3 floats
  float* wpos    = wtop + (size_t)NTOT*NCHUNK*3;       // NTOT floats
  float* partial = wpos + NTOT;                        // 64 floats (+pad)
  unsigned short* tS = (unsigned short*)(partial + 256);
  unsigned short* tR = tS + (size_t)BATCH*HW*CDIM;
  float* snorm = (float*)(tR + (size_t)BATCH*HW*CDIM); // 32*1024 floats
  const size_t need = (size_t)((char*)(snorm + 32*1024) - (char*)d_ws);

  if (ws_size >= need){
    convert_transpose4<<<dim3(512), dim3(512), 0, stream>>>(sketch, refk, tS, tR, snorm);
    fused_gemm_top3_v9<<<dim3(256), dim3(512), 0, stream>>>(tS, tR, snorm, anchor, posidx, wtop, wpos);
  } else {
    fused_gemm_top3_v1<<<dim3(1024), dim3(256), 0, stream>>>(sketch, refk, anchor, posidx, wtop, wpos);
  }
  merge_top3<<<dim3(64), dim3(256), 0, stream>>>(wtop, wpos, partial);
  final_sum<<<dim3(1), dim3(64), 0, stream>>>(partial, out);
}